// Round 9
// baseline (233.021 us; speedup 1.0000x reference)
//
#include <hip/hip_runtime.h>
#include <hip/hip_bf16.h>
#include <math.h>

// ---------------------------------------------------------------------------
// GCN 2-layer forward on MI355X.  ZERO global atomics.
//  convw -> hist_lds (256 blocks, per-block 100KB LDS histogram of packed
//           16-bit counts; rank/edge from LDS atomic return; dump to
//           counts_pb[b][word]) -> gemm1 (mfma, unscaled bf16 h1)
//  -> scan2 (sum counts over 256 blocks/node, emit basecum[b][n] ushort,
//            dinv, block exscan) -> scan_blocksums -> finalize(offsets)
//  -> FUSED [fill_csr: pos = offsets[d]+basecum[b][d]+rank, no atomics
//            || h1 *= dinv]
//  -> agg1 (bf16 gather, +b1, relu) -> mfma_gemm2 (*dinv) -> agg2 (log_softmax)
// R6-R8 evidence: global atomic rate pinned ~1.6e10/s (~1 lane/cy/XCD)
// regardless of padding/ILP/scope -> HW atomic-unit wall. LDS atomics have no
// such wall (per-CU banks). Aliasing: csr/h1a/h2 live in dead counts_pb space.
// ---------------------------------------------------------------------------

typedef unsigned int uint32;
typedef unsigned short ushort16;
typedef __attribute__((ext_vector_type(8))) short bf16x8;
typedef __attribute__((ext_vector_type(4))) float f32x4;

__device__ inline unsigned short f2bf_rne(float f) {
    uint32 x = __float_as_uint(f);
    uint32 r = (x + 0x7fffu + ((x >> 16) & 1u)) >> 16;
    return (unsigned short)r;
}
__device__ inline uint32 pack_bf16x2(float a, float b) {
    return (uint32)f2bf_rne(a) | ((uint32)f2bf_rne(b) << 16);
}
__device__ inline float2 unpack_bf16x2(uint32 u) {
    float2 r;
    r.x = __uint_as_float(u << 16);
    r.y = __uint_as_float(u & 0xffff0000u);
    return r;
}

// W -> bf16 transposed, pair-permuted: slot (t,m) holds logical column
// 32*(t>>1) + 2*m + (t&1), so acc pairs (t=2u,2u+1) pack to adjacent cols.
__global__ __launch_bounds__(256) void convw_k(const float* __restrict__ W1,
                                               const float* __restrict__ W2,
                                               unsigned short* __restrict__ W1t,
                                               unsigned short* __restrict__ W2t) {
    int idx = blockIdx.x * 256 + threadIdx.x;
    if (idx < 128 * 128) {
        int ns = idx >> 7, k = idx & 127;
        int t = ns >> 4, m = ns & 15;
        int col = 32 * (t >> 1) + 2 * m + (t & 1);
        W1t[idx] = f2bf_rne(W1[k * 128 + col]);
    } else {
        int i2 = idx - 128 * 128;
        if (i2 < 64 * 128) {
            int ns = i2 >> 7, k = i2 & 127;
            int t = ns >> 4, m = ns & 15;
            int col = 32 * (t >> 1) + 2 * m + (t & 1);
            W2t[i2] = f2bf_rne(W2[k * 64 + col]);
        }
    }
}

// Per-block LDS histogram (packed 2x16-bit counts/word). Block b owns edges
// [b*chunk, min(E,(b+1)*chunk)). rank = LDS-atomic old count (within block).
__global__ __launch_bounds__(256) void hist_lds_k(const int* __restrict__ dst, int E,
                                                  int NW, int chunk,
                                                  uint32* __restrict__ counts_pb,
                                                  ushort16* __restrict__ rankx) {
    extern __shared__ uint32 sh[];
    const int tid = threadIdx.x;
    const int b   = blockIdx.x;
    for (int i = tid; i < NW; i += 256) sh[i] = 0;
    __syncthreads();
    const int e0 = b * chunk;
    const int e1 = min(E, e0 + chunk);
    int e = e0 + tid;
    for (; e + 768 < e1; e += 1024) {
        int d0 = dst[e];
        int d1 = dst[e + 256];
        int d2 = dst[e + 512];
        int d3 = dst[e + 768];
        uint32 o0 = atomicAdd(&sh[d0 >> 1], (d0 & 1) ? 0x10000u : 1u);
        uint32 o1 = atomicAdd(&sh[d1 >> 1], (d1 & 1) ? 0x10000u : 1u);
        uint32 o2 = atomicAdd(&sh[d2 >> 1], (d2 & 1) ? 0x10000u : 1u);
        uint32 o3 = atomicAdd(&sh[d3 >> 1], (d3 & 1) ? 0x10000u : 1u);
        rankx[e]       = (ushort16)((d0 & 1) ? (o0 >> 16) : (o0 & 0xffffu));
        rankx[e + 256] = (ushort16)((d1 & 1) ? (o1 >> 16) : (o1 & 0xffffu));
        rankx[e + 512] = (ushort16)((d2 & 1) ? (o2 >> 16) : (o2 & 0xffffu));
        rankx[e + 768] = (ushort16)((d3 & 1) ? (o3 >> 16) : (o3 & 0xffffu));
    }
    for (; e < e1; e += 256) {
        int d = dst[e];
        uint32 o = atomicAdd(&sh[d >> 1], (d & 1) ? 0x10000u : 1u);
        rankx[e] = (ushort16)((d & 1) ? (o >> 16) : (o & 0xffffu));
    }
    __syncthreads();
    uint32* dstp = counts_pb + (size_t)b * NW;
    for (int i = tid; i < NW; i += 256) dstp[i] = sh[i];
}

// MFMA GEMM1: h1 = bf16(x @ W1t), unscaled, pair-packed stores.
__global__ __launch_bounds__(256) void gemm1_k(const float* __restrict__ X,
                                               const unsigned short* __restrict__ Wt,
                                               uint32* __restrict__ Yu, int Nrows) {
    constexpr int NCOL = 128;
    constexpr int NT = NCOL / 16;
    const int tid  = threadIdx.x;
    const int wave = tid >> 6;
    const int lane = tid & 63;
    const int m16  = lane & 15;
    const int q    = lane >> 4;
    const int r0   = blockIdx.x * 64 + wave * 16;

    int arow = r0 + m16;
    if (arow >= Nrows) arow = Nrows - 1;

    bf16x8 afrag[4];
#pragma unroll
    for (int kb = 0; kb < 4; ++kb) {
        const float* p = &X[(size_t)arow * 128 + kb * 32 + q * 8];
        float4 u0 = *(const float4*)p;
        float4 u1 = *(const float4*)(p + 4);
        bf16x8 a;
        a[0] = (short)f2bf_rne(u0.x); a[1] = (short)f2bf_rne(u0.y);
        a[2] = (short)f2bf_rne(u0.z); a[3] = (short)f2bf_rne(u0.w);
        a[4] = (short)f2bf_rne(u1.x); a[5] = (short)f2bf_rne(u1.y);
        a[6] = (short)f2bf_rne(u1.z); a[7] = (short)f2bf_rne(u1.w);
        afrag[kb] = a;
    }

    f32x4 acc[NT];
#pragma unroll
    for (int t = 0; t < NT; ++t) acc[t] = (f32x4){0.f, 0.f, 0.f, 0.f};
#pragma unroll
    for (int t = 0; t < NT; ++t) {
        const unsigned short* Bp = &Wt[(size_t)(t * 16 + m16) * 128 + q * 8];
#pragma unroll
        for (int kb = 0; kb < 4; ++kb) {
            bf16x8 bfrag = *(const bf16x8*)&Bp[kb * 32];
            acc[t] = __builtin_amdgcn_mfma_f32_16x16x32_bf16(afrag[kb], bfrag, acc[t], 0, 0, 0);
        }
    }
#pragma unroll
    for (int i = 0; i < 4; ++i) {
        int row = r0 + q * 4 + i;
        if (row < Nrows) {
#pragma unroll
            for (int u = 0; u < NT / 2; ++u)
                Yu[(size_t)row * (NCOL / 2) + u * 16 + m16] =
                    pack_bf16x2(acc[2 * u][i], acc[2 * u + 1][i]);
        }
    }
}

// Sum per-node counts over 256 block-histograms (16-way batched loads),
// emit basecum[b][n] (ushort), dinv, block-local exscan + blocksum.
__global__ __launch_bounds__(256) void scan2_k(const uint32* __restrict__ counts_pb,
                                               int N, int NW,
                                               ushort16* __restrict__ basecum,
                                               int* __restrict__ exscan,
                                               int* __restrict__ blocksum,
                                               float* __restrict__ dinv) {
    __shared__ int sd[256];
    const int tid = threadIdx.x;
    const int n   = blockIdx.x * 256 + tid;
    const int nc  = n < N ? n : N - 1;
    const int w   = nc >> 1;
    const bool hi = (nc & 1) != 0;
    int cum = 0;
    for (int bb = 0; bb < 256; bb += 16) {
        uint32 wv[16];
#pragma unroll
        for (int j = 0; j < 16; ++j)
            wv[j] = counts_pb[(size_t)(bb + j) * NW + w];
#pragma unroll
        for (int j = 0; j < 16; ++j) {
            int c = hi ? (int)(wv[j] >> 16) : (int)(wv[j] & 0xffffu);
            if (n < N) basecum[(size_t)(bb + j) * N + n] = (ushort16)cum;
            cum += c;
        }
    }
    int v = (n < N) ? cum : 0;
    if (n < N) dinv[n] = rsqrtf((float)(v + 1));
    sd[tid] = v;
    __syncthreads();
    for (int off = 1; off < 256; off <<= 1) {
        int t = (tid >= off) ? sd[tid - off] : 0;
        __syncthreads();
        sd[tid] += t;
        __syncthreads();
    }
    if (n < N) exscan[n] = sd[tid] - v;
    if (tid == 255) blocksum[blockIdx.x] = sd[255];
}

__global__ __launch_bounds__(256) void scan_blocksums_k(const int* __restrict__ blocksum, int NB,
                                                        int* __restrict__ blockoff,
                                                        int* __restrict__ offsets_last) {
    __shared__ int sd[256];
    const int tid = threadIdx.x;
    int v = (tid < NB) ? blocksum[tid] : 0;
    sd[tid] = v;
    __syncthreads();
    for (int off = 1; off < 256; off <<= 1) {
        int t = (tid >= off) ? sd[tid - off] : 0;
        __syncthreads();
        sd[tid] += t;
        __syncthreads();
    }
    if (tid < NB) blockoff[tid] = sd[tid] - v;
    if (tid == 255) *offsets_last = sd[255];
}

__global__ __launch_bounds__(256) void finalize_k(const int* __restrict__ exscan,
                                                  const int* __restrict__ blockoff, int N,
                                                  int* __restrict__ offsets) {
    const int gid = blockIdx.x * 256 + threadIdx.x;
    if (gid < N) offsets[gid] = blockoff[blockIdx.x] + exscan[gid];
}

// FUSED: blocks [0,256): fill CSR, pos = offsets[d] + basecum[b][d] + rank.
//        blocks [256,256+SB): scale h1 (packed bf16x2) by dinv[row], x4 ILP.
__global__ __launch_bounds__(256) void fill_scale_k(const int* __restrict__ src,
                                                    const int* __restrict__ dst, int E,
                                                    int chunk, int N,
                                                    const ushort16* __restrict__ rankx,
                                                    const ushort16* __restrict__ basecum,
                                                    const int* __restrict__ offsets,
                                                    int* __restrict__ csr_src,
                                                    uint32* __restrict__ H, int U,
                                                    const float* __restrict__ dinv,
                                                    int SB) {
    if ((int)blockIdx.x < 256) {
        const int b  = blockIdx.x;
        const ushort16* bc = basecum + (size_t)b * N;
        const int e0 = b * chunk;
        const int e1 = min(E, e0 + chunk);
        int e = e0 + threadIdx.x;
        for (; e + 768 < e1; e += 1024) {
#pragma unroll
            for (int j = 0; j < 4; ++j) {
                int ej = e + j * 256;
                int d = dst[ej];
                int pos = offsets[d] + (int)bc[d] + (int)rankx[ej];
                csr_src[pos] = src[ej];
            }
        }
        for (; e < e1; e += 256) {
            int d = dst[e];
            int pos = offsets[d] + (int)bc[d] + (int)rankx[e];
            csr_src[pos] = src[e];
        }
        return;
    }
    const int T2 = SB * 256;
    const int i = ((int)blockIdx.x - 256) * 256 + threadIdx.x;
#pragma unroll
    for (int j = 0; j < 4; ++j) {
        int idx = i + j * T2;
        if (idx < U) {
            float dn = dinv[idx >> 6];
            float2 f = unpack_bf16x2(H[idx]);
            H[idx] = pack_bf16x2(f.x * dn, f.y * dn);
        }
    }
}

// MFMA GEMM2: h2[r,:] = bf16( (h1a[r,:128] @ W2t) * dinv[r] ), pair-packed.
__global__ __launch_bounds__(256) void mfma_gemm2_k(const unsigned short* __restrict__ X,
                                                    const unsigned short* __restrict__ Wt,
                                                    const float* __restrict__ dinv,
                                                    uint32* __restrict__ Yu, int Nrows) {
    constexpr int NCOL = 64;
    constexpr int NT = NCOL / 16;
    const int tid  = threadIdx.x;
    const int wave = tid >> 6;
    const int lane = tid & 63;
    const int m16  = lane & 15;
    const int q    = lane >> 4;
    const int r0   = blockIdx.x * 64 + wave * 16;

    int arow = r0 + m16;
    if (arow >= Nrows) arow = Nrows - 1;

    bf16x8 afrag[4];
#pragma unroll
    for (int kb = 0; kb < 4; ++kb)
        afrag[kb] = *(const bf16x8*)&X[(size_t)arow * 128 + kb * 32 + q * 8];

    f32x4 acc[NT];
#pragma unroll
    for (int t = 0; t < NT; ++t) acc[t] = (f32x4){0.f, 0.f, 0.f, 0.f};
#pragma unroll
    for (int t = 0; t < NT; ++t) {
        const unsigned short* Bp = &Wt[(size_t)(t * 16 + m16) * 128 + q * 8];
#pragma unroll
        for (int kb = 0; kb < 4; ++kb) {
            bf16x8 bfrag = *(const bf16x8*)&Bp[kb * 32];
            acc[t] = __builtin_amdgcn_mfma_f32_16x16x32_bf16(afrag[kb], bfrag, acc[t], 0, 0, 0);
        }
    }
#pragma unroll
    for (int i = 0; i < 4; ++i) {
        int row = r0 + q * 4 + i;
        if (row < Nrows) {
            float dn = dinv[row];
#pragma unroll
            for (int u = 0; u < NT / 2; ++u)
                Yu[(size_t)row * (NCOL / 2) + u * 16 + m16] =
                    pack_bf16x2(acc[2 * u][i] * dn, acc[2 * u + 1][i] * dn);
        }
    }
}

// Layer-1 aggregation: 64 lanes/node, 2 ch/lane, 4 nodes/block, x4 unroll.
__global__ __launch_bounds__(256) void agg1_k(const unsigned short* __restrict__ hs,
                                              const int* __restrict__ offsets,
                                              const int* __restrict__ csr_src,
                                              const float* __restrict__ dinv,
                                              const float* __restrict__ b1,
                                              unsigned short* __restrict__ out, int N) {
    const int tid  = threadIdx.x;
    const int node = blockIdx.x * 4 + (tid >> 6);
    const int lane = tid & 63;
    if (node >= N) return;
    const uint32* T = (const uint32*)hs;
    const int start = offsets[node];
    const int end   = offsets[node + 1];
    const float dn  = dinv[node];
    float2 self = unpack_bf16x2(T[(size_t)node * 64 + lane]);
    float ax0 = self.x, ay0 = self.y;
    float ax1 = 0.f, ay1 = 0.f, ax2 = 0.f, ay2 = 0.f, ax3 = 0.f, ay3 = 0.f;
    int p = start;
    for (; p + 3 < end; p += 4) {
        int s0 = csr_src[p];
        int s1 = csr_src[p + 1];
        int s2 = csr_src[p + 2];
        int s3 = csr_src[p + 3];
        float2 f0 = unpack_bf16x2(T[(size_t)s0 * 64 + lane]);
        float2 f1 = unpack_bf16x2(T[(size_t)s1 * 64 + lane]);
        float2 f2 = unpack_bf16x2(T[(size_t)s2 * 64 + lane]);
        float2 f3 = unpack_bf16x2(T[(size_t)s3 * 64 + lane]);
        ax0 += f0.x; ay0 += f0.y;
        ax1 += f1.x; ay1 += f1.y;
        ax2 += f2.x; ay2 += f2.y;
        ax3 += f3.x; ay3 += f3.y;
    }
    for (; p < end; ++p) {
        float2 f = unpack_bf16x2(T[(size_t)csr_src[p] * 64 + lane]);
        ax1 += f.x; ay1 += f.y;
    }
    float2 bb = ((const float2*)b1)[lane];
    float vx = ((ax0 + ax1) + (ax2 + ax3)) * dn + bb.x;
    float vy = ((ay0 + ay1) + (ay2 + ay3)) * dn + bb.y;
    vx = vx > 0.f ? vx : 0.f;
    vy = vy > 0.f ? vy : 0.f;
    ((uint32*)out)[(size_t)node * 64 + lane] = pack_bf16x2(vx, vy);
}

// Layer-2 aggregation + bias + log_softmax. 32 lanes/node, 8 nodes/block.
__global__ __launch_bounds__(256) void agg2_k(const unsigned short* __restrict__ hs,
                                              const int* __restrict__ offsets,
                                              const int* __restrict__ csr_src,
                                              const float* __restrict__ dinv,
                                              const float* __restrict__ b2,
                                              float* __restrict__ out, int N) {
    const int tid  = threadIdx.x;
    const int node = blockIdx.x * 8 + (tid >> 5);
    const int l    = tid & 31;
    if (node >= N) return;
    const uint32* T = (const uint32*)hs;
    const int start = offsets[node];
    const int end   = offsets[node + 1];
    const float dn  = dinv[node];
    float2 self = unpack_bf16x2(T[(size_t)node * 32 + l]);
    float ax0 = self.x, ay0 = self.y;
    float ax1 = 0.f, ay1 = 0.f, ax2 = 0.f, ay2 = 0.f, ax3 = 0.f, ay3 = 0.f;
    int p = start;
    for (; p + 3 < end; p += 4) {
        int s0 = csr_src[p];
        int s1 = csr_src[p + 1];
        int s2 = csr_src[p + 2];
        int s3 = csr_src[p + 3];
        float2 f0 = unpack_bf16x2(T[(size_t)s0 * 32 + l]);
        float2 f1 = unpack_bf16x2(T[(size_t)s1 * 32 + l]);
        float2 f2 = unpack_bf16x2(T[(size_t)s2 * 32 + l]);
        float2 f3 = unpack_bf16x2(T[(size_t)s3 * 32 + l]);
        ax0 += f0.x; ay0 += f0.y;
        ax1 += f1.x; ay1 += f1.y;
        ax2 += f2.x; ay2 += f2.y;
        ax3 += f3.x; ay3 += f3.y;
    }
    for (; p < end; ++p) {
        float2 f = unpack_bf16x2(T[(size_t)csr_src[p] * 32 + l]);
        ax1 += f.x; ay1 += f.y;
    }
    float2 bb = ((const float2*)b2)[l];
    float vx = ((ax0 + ax1) + (ax2 + ax3)) * dn + bb.x;
    float vy = ((ay0 + ay1) + (ay2 + ay3)) * dn + bb.y;
    float m = fmaxf(vx, vy);
#pragma unroll
    for (int off = 16; off > 0; off >>= 1) m = fmaxf(m, __shfl_xor(m, off, 64));
    float ex = __expf(vx - m) + __expf(vy - m);
    float ssum = ex;
#pragma unroll
    for (int off = 16; off > 0; off >>= 1) ssum += __shfl_xor(ssum, off, 64);
    float lse = m + __logf(ssum);
    float2 o = {vx - lse, vy - lse};
    ((float2*)out)[(size_t)node * 32 + l] = o;
}

extern "C" void kernel_launch(void* const* d_in, const int* in_sizes, int n_in,
                              void* d_out, int out_size, void* d_ws, size_t ws_size,
                              hipStream_t stream) {
    const float* x  = (const float*)d_in[0];
    const int*   ei = (const int*)d_in[1];
    const float* W1 = (const float*)d_in[2];
    const float* b1 = (const float*)d_in[3];
    const float* W2 = (const float*)d_in[4];
    const float* b2 = (const float*)d_in[5];
    float* out = (float*)d_out;

    const int N = in_sizes[0] / 128;  // 50000
    const int E = in_sizes[1] / 2;    // 800000
    const int* src = ei;
    const int* dst = ei + E;
    const int NB = (N + 255) / 256;       // 196
    const int NW = (N + 1) / 2;           // 25000 packed count words
    const int chunk = (E + 255) / 256;    // 3125 edges per hist/fill block

    char* ws = (char*)d_ws;
    auto alloc = [&](size_t bytes) -> char* {
        char* p = ws;
        ws += (bytes + 255) & ~(size_t)255;
        return p;
    };
    unsigned short* h1 = (unsigned short*)alloc((size_t)N * 128 * 2);  // 12.8MB
    // Region A: counts_pb (hist->scan2), then reused for csr/h1a/h2.
    char* regA = alloc((size_t)256 * NW * 4);                           // 25.6MB
    uint32* counts_pb = (uint32*)regA;
    int* csr_src = (int*)regA;                                          // E*4 = 3.2MB
    unsigned short* h1a = (unsigned short*)(regA + (((size_t)E * 4 + 255) & ~(size_t)255));
    unsigned short* h2  = (unsigned short*)((char*)h1a + (size_t)N * 128 * 2);
    // Region B: basecum (scan2->fill).
    ushort16* basecum = (ushort16*)alloc((size_t)256 * N * 2);          // 25.6MB
    ushort16* rankx   = (ushort16*)alloc((size_t)E * 2);                // 1.6MB
    float* dinv     = (float*)alloc((size_t)N * 4);
    int*   exscan   = (int*)alloc((size_t)N * 4);
    int*   blocksum = (int*)alloc((size_t)NB * 4);
    int*   blockoff = (int*)alloc((size_t)NB * 4);
    int*   offsets  = (int*)alloc((size_t)(N + 1) * 4);
    unsigned short* W1t = (unsigned short*)alloc(128 * 128 * 2);
    unsigned short* W2t = (unsigned short*)alloc(64 * 128 * 2);

    const int GB = (N + 63) / 64;          // 782 gemm blocks
    const int U  = N * 64;                 // h1 packed-uint count
    const int SB = (U + 1023) / 1024;      // scale blocks (x4 ILP)

    convw_k<<<(128 * 128 + 64 * 128 + 255) / 256, 256, 0, stream>>>(W1, W2, W1t, W2t);
    hist_lds_k<<<256, 256, NW * 4, stream>>>(dst, E, NW, chunk, counts_pb, rankx);
    gemm1_k<<<GB, 256, 0, stream>>>(x, W1t, (uint32*)h1, N);
    scan2_k<<<NB, 256, 0, stream>>>(counts_pb, N, NW, basecum, exscan, blocksum, dinv);
    scan_blocksums_k<<<1, 256, 0, stream>>>(blocksum, NB, blockoff, offsets + N);
    finalize_k<<<NB, 256, 0, stream>>>(exscan, blockoff, N, offsets);
    fill_scale_k<<<256 + SB, 256, 0, stream>>>(src, dst, E, chunk, N, rankx, basecum,
                                               offsets, csr_src, (uint32*)h1, U, dinv, SB);
    agg1_k<<<(N + 3) / 4, 256, 0, stream>>>(h1, offsets, csr_src, dinv, b1, h1a, N);
    mfma_gemm2_k<<<GB, 256, 0, stream>>>(h1a, W2t, dinv, (uint32*)h2, N);
    agg2_k<<<(N + 7) / 8, 256, 0, stream>>>(h2, offsets, csr_src, dinv, b2, out, N);
}

// Round 10
// 215.194 us; speedup vs baseline: 1.0828x; 1.0828x over previous
//
#include <hip/hip_runtime.h>
#include <hip/hip_bf16.h>
#include <math.h>

// ---------------------------------------------------------------------------
// GCN 2-layer forward on MI355X.  ZERO global atomics.
//  convw -> hist_lds (64 blocks x 100KB LDS packed 16-bit histograms;
//           rank/edge from LDS-atomic return; dump counts_pb[64][NW])
//  -> scan2 (sum 64 replicas/node -> basecum[64][N] ushort, dinv, exscan)
//  -> scan_blocksums -> finalize(offsets)
//  -> FUSED [fill_csr (256 blocks, pos = offsets[d]+basecum[b][d]+rank,
//            no atomics)  ||  mfma_gemm1 (x @ W1t, *dinv folded, bf16 h1)]
//  -> agg1 (bf16 gather, +b1, relu) -> mfma_gemm2 (*dinv) -> agg2 (log_softmax)
// R6-R8: global atomic rate pinned ~1.6e10/s regardless of padding/ILP/scope
// (HW atomic-unit wall) -> all counting via LDS atomics. R9 lesson: 256
// histogram replicas cost 77MB bookkeeping; 64 replicas cut it 4x. gemm1
// rides inside the scatter-latency-bound fill kernel (both LDS-free).
// ---------------------------------------------------------------------------

typedef unsigned int uint32;
typedef unsigned short ushort16;
typedef __attribute__((ext_vector_type(8))) short bf16x8;
typedef __attribute__((ext_vector_type(4))) float f32x4;

__device__ inline unsigned short f2bf_rne(float f) {
    uint32 x = __float_as_uint(f);
    uint32 r = (x + 0x7fffu + ((x >> 16) & 1u)) >> 16;
    return (unsigned short)r;
}
__device__ inline uint32 pack_bf16x2(float a, float b) {
    return (uint32)f2bf_rne(a) | ((uint32)f2bf_rne(b) << 16);
}
__device__ inline float2 unpack_bf16x2(uint32 u) {
    float2 r;
    r.x = __uint_as_float(u << 16);
    r.y = __uint_as_float(u & 0xffff0000u);
    return r;
}

// W -> bf16 transposed, pair-permuted: slot (t,m) holds logical column
// 32*(t>>1) + 2*m + (t&1), so acc pairs (t=2u,2u+1) pack to adjacent cols.
__global__ __launch_bounds__(256) void convw_k(const float* __restrict__ W1,
                                               const float* __restrict__ W2,
                                               unsigned short* __restrict__ W1t,
                                               unsigned short* __restrict__ W2t) {
    int idx = blockIdx.x * 256 + threadIdx.x;
    if (idx < 128 * 128) {
        int ns = idx >> 7, k = idx & 127;
        int t = ns >> 4, m = ns & 15;
        int col = 32 * (t >> 1) + 2 * m + (t & 1);
        W1t[idx] = f2bf_rne(W1[k * 128 + col]);
    } else {
        int i2 = idx - 128 * 128;
        if (i2 < 64 * 128) {
            int ns = i2 >> 7, k = i2 & 127;
            int t = ns >> 4, m = ns & 15;
            int col = 32 * (t >> 1) + 2 * m + (t & 1);
            W2t[i2] = f2bf_rne(W2[k * 64 + col]);
        }
    }
}

// 64 blocks, each owns edges [b*chunk, min(E,(b+1)*chunk)). Packed 2x16-bit
// counts in 100KB LDS; rank = LDS-atomic old count (within block, per node).
__global__ __launch_bounds__(256) void hist_lds_k(const int* __restrict__ dst, int E,
                                                  int NW, int chunk,
                                                  uint32* __restrict__ counts_pb,
                                                  ushort16* __restrict__ rankx) {
    extern __shared__ uint32 sh[];
    const int tid = threadIdx.x;
    const int b   = blockIdx.x;
    for (int i = tid; i < NW; i += 256) sh[i] = 0;
    __syncthreads();
    const int e0 = b * chunk;
    const int e1 = min(E, e0 + chunk);
    int e = e0 + tid;
    for (; e + 768 < e1; e += 1024) {
        int d0 = dst[e];
        int d1 = dst[e + 256];
        int d2 = dst[e + 512];
        int d3 = dst[e + 768];
        uint32 o0 = atomicAdd(&sh[d0 >> 1], (d0 & 1) ? 0x10000u : 1u);
        uint32 o1 = atomicAdd(&sh[d1 >> 1], (d1 & 1) ? 0x10000u : 1u);
        uint32 o2 = atomicAdd(&sh[d2 >> 1], (d2 & 1) ? 0x10000u : 1u);
        uint32 o3 = atomicAdd(&sh[d3 >> 1], (d3 & 1) ? 0x10000u : 1u);
        rankx[e]       = (ushort16)((d0 & 1) ? (o0 >> 16) : (o0 & 0xffffu));
        rankx[e + 256] = (ushort16)((d1 & 1) ? (o1 >> 16) : (o1 & 0xffffu));
        rankx[e + 512] = (ushort16)((d2 & 1) ? (o2 >> 16) : (o2 & 0xffffu));
        rankx[e + 768] = (ushort16)((d3 & 1) ? (o3 >> 16) : (o3 & 0xffffu));
    }
    for (; e < e1; e += 256) {
        int d = dst[e];
        uint32 o = atomicAdd(&sh[d >> 1], (d & 1) ? 0x10000u : 1u);
        rankx[e] = (ushort16)((d & 1) ? (o >> 16) : (o & 0xffffu));
    }
    __syncthreads();
    uint32* dstp = counts_pb + (size_t)b * NW;
    for (int i = tid; i < NW; i += 256) dstp[i] = sh[i];
}

// Sum per-node counts over 64 block-histograms (16-way batched loads),
// emit basecum[b][n] (ushort), dinv, block-local exscan + blocksum.
__global__ __launch_bounds__(256) void scan2_k(const uint32* __restrict__ counts_pb,
                                               int N, int NW,
                                               ushort16* __restrict__ basecum,
                                               int* __restrict__ exscan,
                                               int* __restrict__ blocksum,
                                               float* __restrict__ dinv) {
    __shared__ int sd[256];
    const int tid = threadIdx.x;
    const int n   = blockIdx.x * 256 + tid;
    const int nc  = n < N ? n : N - 1;
    const int w   = nc >> 1;
    const bool hi = (nc & 1) != 0;
    int cum = 0;
    for (int bb = 0; bb < 64; bb += 16) {
        uint32 wv[16];
#pragma unroll
        for (int j = 0; j < 16; ++j)
            wv[j] = counts_pb[(size_t)(bb + j) * NW + w];
#pragma unroll
        for (int j = 0; j < 16; ++j) {
            int c = hi ? (int)(wv[j] >> 16) : (int)(wv[j] & 0xffffu);
            if (n < N) basecum[(size_t)(bb + j) * N + n] = (ushort16)cum;
            cum += c;
        }
    }
    int v = (n < N) ? cum : 0;
    if (n < N) dinv[n] = rsqrtf((float)(v + 1));
    sd[tid] = v;
    __syncthreads();
    for (int off = 1; off < 256; off <<= 1) {
        int t = (tid >= off) ? sd[tid - off] : 0;
        __syncthreads();
        sd[tid] += t;
        __syncthreads();
    }
    if (n < N) exscan[n] = sd[tid] - v;
    if (tid == 255) blocksum[blockIdx.x] = sd[255];
}

__global__ __launch_bounds__(256) void scan_blocksums_k(const int* __restrict__ blocksum, int NB,
                                                        int* __restrict__ blockoff,
                                                        int* __restrict__ offsets_last) {
    __shared__ int sd[256];
    const int tid = threadIdx.x;
    int v = (tid < NB) ? blocksum[tid] : 0;
    sd[tid] = v;
    __syncthreads();
    for (int off = 1; off < 256; off <<= 1) {
        int t = (tid >= off) ? sd[tid - off] : 0;
        __syncthreads();
        sd[tid] += t;
        __syncthreads();
    }
    if (tid < NB) blockoff[tid] = sd[tid] - v;
    if (tid == 255) *offsets_last = sd[255];
}

__global__ __launch_bounds__(256) void finalize_k(const int* __restrict__ exscan,
                                                  const int* __restrict__ blockoff, int N,
                                                  int* __restrict__ offsets) {
    const int gid = blockIdx.x * 256 + threadIdx.x;
    if (gid < N) offsets[gid] = blockoff[blockIdx.x] + exscan[gid];
}

// FUSED: blocks [0,256): fill CSR; fill block f covers quarter f&3 of hist
//   chunk b=f>>2:  pos = offsets[d] + basecum[b][d] + rank.  No atomics.
// blocks [256,256+GB): mfma gemm1 h1 = bf16((x @ W1t) * dinv) — dinv is
//   known by now, so the scale pass is folded into the epilogue.
__global__ __launch_bounds__(256) void fill_gemm1_k(const int* __restrict__ src,
                                                    const int* __restrict__ dst, int E,
                                                    int chunk, int N,
                                                    const ushort16* __restrict__ rankx,
                                                    const ushort16* __restrict__ basecum,
                                                    const int* __restrict__ offsets,
                                                    int* __restrict__ csr_src,
                                                    const float* __restrict__ X,
                                                    const unsigned short* __restrict__ Wt,
                                                    const float* __restrict__ dinv,
                                                    uint32* __restrict__ Yu, int Nrows) {
    if ((int)blockIdx.x < 256) {
        const int f  = blockIdx.x;
        const int b  = f >> 2;
        const ushort16* bc = basecum + (size_t)b * N;
        const int q4 = chunk >> 2;
        const int e0 = b * chunk + (f & 3) * q4;
        const int e1 = min(E, e0 + q4);
        int e = e0 + threadIdx.x;
        for (; e + 768 < e1; e += 1024) {
#pragma unroll
            for (int j = 0; j < 4; ++j) {
                int ej = e + j * 256;
                int d = dst[ej];
                int pos = offsets[d] + (int)bc[d] + (int)rankx[ej];
                csr_src[pos] = src[ej];
            }
        }
        for (; e < e1; e += 256) {
            int d = dst[e];
            int pos = offsets[d] + (int)bc[d] + (int)rankx[e];
            csr_src[pos] = src[e];
        }
        return;
    }
    // ---- gemm1 part (NCOL=128, fp32 A converted in-register, *dinv) ----
    constexpr int NCOL = 128;
    constexpr int NT = NCOL / 16;
    const int tid  = threadIdx.x;
    const int wave = tid >> 6;
    const int lane = tid & 63;
    const int m16  = lane & 15;
    const int q    = lane >> 4;
    const int r0   = ((int)blockIdx.x - 256) * 64 + wave * 16;

    int arow = r0 + m16;
    if (arow >= Nrows) arow = Nrows - 1;

    bf16x8 afrag[4];
#pragma unroll
    for (int kb = 0; kb < 4; ++kb) {
        const float* p = &X[(size_t)arow * 128 + kb * 32 + q * 8];
        float4 u0 = *(const float4*)p;
        float4 u1 = *(const float4*)(p + 4);
        bf16x8 a;
        a[0] = (short)f2bf_rne(u0.x); a[1] = (short)f2bf_rne(u0.y);
        a[2] = (short)f2bf_rne(u0.z); a[3] = (short)f2bf_rne(u0.w);
        a[4] = (short)f2bf_rne(u1.x); a[5] = (short)f2bf_rne(u1.y);
        a[6] = (short)f2bf_rne(u1.z); a[7] = (short)f2bf_rne(u1.w);
        afrag[kb] = a;
    }

    f32x4 acc[NT];
#pragma unroll
    for (int t = 0; t < NT; ++t) acc[t] = (f32x4){0.f, 0.f, 0.f, 0.f};
#pragma unroll
    for (int t = 0; t < NT; ++t) {
        const unsigned short* Bp = &Wt[(size_t)(t * 16 + m16) * 128 + q * 8];
#pragma unroll
        for (int kb = 0; kb < 4; ++kb) {
            bf16x8 bfrag = *(const bf16x8*)&Bp[kb * 32];
            acc[t] = __builtin_amdgcn_mfma_f32_16x16x32_bf16(afrag[kb], bfrag, acc[t], 0, 0, 0);
        }
    }
#pragma unroll
    for (int i = 0; i < 4; ++i) {
        int row = r0 + q * 4 + i;
        if (row < Nrows) {
            float dn = dinv[row];
#pragma unroll
            for (int u = 0; u < NT / 2; ++u)
                Yu[(size_t)row * (NCOL / 2) + u * 16 + m16] =
                    pack_bf16x2(acc[2 * u][i] * dn, acc[2 * u + 1][i] * dn);
        }
    }
}

// MFMA GEMM2: h2[r,:] = bf16( (h1a[r,:128] @ W2t) * dinv[r] ), pair-packed.
__global__ __launch_bounds__(256) void mfma_gemm2_k(const unsigned short* __restrict__ X,
                                                    const unsigned short* __restrict__ Wt,
                                                    const float* __restrict__ dinv,
                                                    uint32* __restrict__ Yu, int Nrows) {
    constexpr int NCOL = 64;
    constexpr int NT = NCOL / 16;
    const int tid  = threadIdx.x;
    const int wave = tid >> 6;
    const int lane = tid & 63;
    const int m16  = lane & 15;
    const int q    = lane >> 4;
    const int r0   = blockIdx.x * 64 + wave * 16;

    int arow = r0 + m16;
    if (arow >= Nrows) arow = Nrows - 1;

    bf16x8 afrag[4];
#pragma unroll
    for (int kb = 0; kb < 4; ++kb)
        afrag[kb] = *(const bf16x8*)&X[(size_t)arow * 128 + kb * 32 + q * 8];

    f32x4 acc[NT];
#pragma unroll
    for (int t = 0; t < NT; ++t) acc[t] = (f32x4){0.f, 0.f, 0.f, 0.f};
#pragma unroll
    for (int t = 0; t < NT; ++t) {
        const unsigned short* Bp = &Wt[(size_t)(t * 16 + m16) * 128 + q * 8];
#pragma unroll
        for (int kb = 0; kb < 4; ++kb) {
            bf16x8 bfrag = *(const bf16x8*)&Bp[kb * 32];
            acc[t] = __builtin_amdgcn_mfma_f32_16x16x32_bf16(afrag[kb], bfrag, acc[t], 0, 0, 0);
        }
    }
#pragma unroll
    for (int i = 0; i < 4; ++i) {
        int row = r0 + q * 4 + i;
        if (row < Nrows) {
            float dn = dinv[row];
#pragma unroll
            for (int u = 0; u < NT / 2; ++u)
                Yu[(size_t)row * (NCOL / 2) + u * 16 + m16] =
                    pack_bf16x2(acc[2 * u][i] * dn, acc[2 * u + 1][i] * dn);
        }
    }
}

// Layer-1 aggregation: 64 lanes/node, 2 ch/lane, 4 nodes/block, x4 unroll.
__global__ __launch_bounds__(256) void agg1_k(const unsigned short* __restrict__ hs,
                                              const int* __restrict__ offsets,
                                              const int* __restrict__ csr_src,
                                              const float* __restrict__ dinv,
                                              const float* __restrict__ b1,
                                              unsigned short* __restrict__ out, int N) {
    const int tid  = threadIdx.x;
    const int node = blockIdx.x * 4 + (tid >> 6);
    const int lane = tid & 63;
    if (node >= N) return;
    const uint32* T = (const uint32*)hs;
    const int start = offsets[node];
    const int end   = offsets[node + 1];
    const float dn  = dinv[node];
    float2 self = unpack_bf16x2(T[(size_t)node * 64 + lane]);
    float ax0 = self.x, ay0 = self.y;
    float ax1 = 0.f, ay1 = 0.f, ax2 = 0.f, ay2 = 0.f, ax3 = 0.f, ay3 = 0.f;
    int p = start;
    for (; p + 3 < end; p += 4) {
        int s0 = csr_src[p];
        int s1 = csr_src[p + 1];
        int s2 = csr_src[p + 2];
        int s3 = csr_src[p + 3];
        float2 f0 = unpack_bf16x2(T[(size_t)s0 * 64 + lane]);
        float2 f1 = unpack_bf16x2(T[(size_t)s1 * 64 + lane]);
        float2 f2 = unpack_bf16x2(T[(size_t)s2 * 64 + lane]);
        float2 f3 = unpack_bf16x2(T[(size_t)s3 * 64 + lane]);
        ax0 += f0.x; ay0 += f0.y;
        ax1 += f1.x; ay1 += f1.y;
        ax2 += f2.x; ay2 += f2.y;
        ax3 += f3.x; ay3 += f3.y;
    }
    for (; p < end; ++p) {
        float2 f = unpack_bf16x2(T[(size_t)csr_src[p] * 64 + lane]);
        ax1 += f.x; ay1 += f.y;
    }
    float2 bb = ((const float2*)b1)[lane];
    float vx = ((ax0 + ax1) + (ax2 + ax3)) * dn + bb.x;
    float vy = ((ay0 + ay1) + (ay2 + ay3)) * dn + bb.y;
    vx = vx > 0.f ? vx : 0.f;
    vy = vy > 0.f ? vy : 0.f;
    ((uint32*)out)[(size_t)node * 64 + lane] = pack_bf16x2(vx, vy);
}

// Layer-2 aggregation + bias + log_softmax. 32 lanes/node, 8 nodes/block.
__global__ __launch_bounds__(256) void agg2_k(const unsigned short* __restrict__ hs,
                                              const int* __restrict__ offsets,
                                              const int* __restrict__ csr_src,
                                              const float* __restrict__ dinv,
                                              const float* __restrict__ b2,
                                              float* __restrict__ out, int N) {
    const int tid  = threadIdx.x;
    const int node = blockIdx.x * 8 + (tid >> 5);
    const int l    = tid & 31;
    if (node >= N) return;
    const uint32* T = (const uint32*)hs;
    const int start = offsets[node];
    const int end   = offsets[node + 1];
    const float dn  = dinv[node];
    float2 self = unpack_bf16x2(T[(size_t)node * 32 + l]);
    float ax0 = self.x, ay0 = self.y;
    float ax1 = 0.f, ay1 = 0.f, ax2 = 0.f, ay2 = 0.f, ax3 = 0.f, ay3 = 0.f;
    int p = start;
    for (; p + 3 < end; p += 4) {
        int s0 = csr_src[p];
        int s1 = csr_src[p + 1];
        int s2 = csr_src[p + 2];
        int s3 = csr_src[p + 3];
        float2 f0 = unpack_bf16x2(T[(size_t)s0 * 32 + l]);
        float2 f1 = unpack_bf16x2(T[(size_t)s1 * 32 + l]);
        float2 f2 = unpack_bf16x2(T[(size_t)s2 * 32 + l]);
        float2 f3 = unpack_bf16x2(T[(size_t)s3 * 32 + l]);
        ax0 += f0.x; ay0 += f0.y;
        ax1 += f1.x; ay1 += f1.y;
        ax2 += f2.x; ay2 += f2.y;
        ax3 += f3.x; ay3 += f3.y;
    }
    for (; p < end; ++p) {
        float2 f = unpack_bf16x2(T[(size_t)csr_src[p] * 32 + l]);
        ax1 += f.x; ay1 += f.y;
    }
    float2 bb = ((const float2*)b2)[l];
    float vx = ((ax0 + ax1) + (ax2 + ax3)) * dn + bb.x;
    float vy = ((ay0 + ay1) + (ay2 + ay3)) * dn + bb.y;
    float m = fmaxf(vx, vy);
#pragma unroll
    for (int off = 16; off > 0; off >>= 1) m = fmaxf(m, __shfl_xor(m, off, 64));
    float ex = __expf(vx - m) + __expf(vy - m);
    float ssum = ex;
#pragma unroll
    for (int off = 16; off > 0; off >>= 1) ssum += __shfl_xor(ssum, off, 64);
    float lse = m + __logf(ssum);
    float2 o = {vx - lse, vy - lse};
    ((float2*)out)[(size_t)node * 32 + l] = o;
}

extern "C" void kernel_launch(void* const* d_in, const int* in_sizes, int n_in,
                              void* d_out, int out_size, void* d_ws, size_t ws_size,
                              hipStream_t stream) {
    const float* x  = (const float*)d_in[0];
    const int*   ei = (const int*)d_in[1];
    const float* W1 = (const float*)d_in[2];
    const float* b1 = (const float*)d_in[3];
    const float* W2 = (const float*)d_in[4];
    const float* b2 = (const float*)d_in[5];
    float* out = (float*)d_out;

    const int N = in_sizes[0] / 128;  // 50000
    const int E = in_sizes[1] / 2;    // 800000
    const int* src = ei;
    const int* dst = ei + E;
    const int NB = (N + 255) / 256;       // 196
    const int NW = (N + 1) / 2;           // 25000 packed count words
    const int NHB = 64;                   // histogram blocks / replicas
    const int chunk = (E + NHB - 1) / NHB;  // 12500 edges per hist block

    char* ws = (char*)d_ws;
    auto alloc = [&](size_t bytes) -> char* {
        char* p = ws;
        ws += (bytes + 255) & ~(size_t)255;
        return p;
    };
    unsigned short* h1  = (unsigned short*)alloc((size_t)N * 128 * 2);   // 12.8MB
    unsigned short* h1a = (unsigned short*)alloc((size_t)N * 128 * 2);   // 12.8MB
    unsigned short* h2  = (unsigned short*)alloc((size_t)N * 64 * 2);    // 6.4MB
    uint32* counts_pb = (uint32*)alloc((size_t)NHB * NW * 4);            // 6.4MB
    ushort16* basecum = (ushort16*)alloc((size_t)NHB * N * 2);           // 6.4MB
    ushort16* rankx   = (ushort16*)alloc((size_t)E * 2);                 // 1.6MB
    int*   csr_src  = (int*)alloc((size_t)E * 4);                        // 3.2MB
    float* dinv     = (float*)alloc((size_t)N * 4);
    int*   exscan   = (int*)alloc((size_t)N * 4);
    int*   blocksum = (int*)alloc((size_t)NB * 4);
    int*   blockoff = (int*)alloc((size_t)NB * 4);
    int*   offsets  = (int*)alloc((size_t)(N + 1) * 4);
    unsigned short* W1t = (unsigned short*)alloc(128 * 128 * 2);
    unsigned short* W2t = (unsigned short*)alloc(64 * 128 * 2);

    const int GB = (N + 63) / 64;          // 782 gemm blocks

    convw_k<<<(128 * 128 + 64 * 128 + 255) / 256, 256, 0, stream>>>(W1, W2, W1t, W2t);
    hist_lds_k<<<NHB, 256, NW * 4, stream>>>(dst, E, NW, chunk, counts_pb, rankx);
    scan2_k<<<NB, 256, 0, stream>>>(counts_pb, N, NW, basecum, exscan, blocksum, dinv);
    scan_blocksums_k<<<1, 256, 0, stream>>>(blocksum, NB, blockoff, offsets + N);
    finalize_k<<<NB, 256, 0, stream>>>(exscan, blockoff, N, offsets);
    fill_gemm1_k<<<256 + GB, 256, 0, stream>>>(src, dst, E, chunk, N, rankx, basecum,
                                               offsets, csr_src, x, W1t, dinv,
                                               (uint32*)h1, N);
    agg1_k<<<(N + 3) / 4, 256, 0, stream>>>(h1, offsets, csr_src, dinv, b1, h1a, N);
    mfma_gemm2_k<<<GB, 256, 0, stream>>>(h1a, W2t, dinv, (uint32*)h2, N);
    agg2_k<<<(N + 7) / 8, 256, 0, stream>>>(h2, offsets, csr_src, dinv, b2, out, N);
}

// Round 11
// 209.911 us; speedup vs baseline: 1.1101x; 1.0252x over previous
//
#include <hip/hip_runtime.h>
#include <hip/hip_bf16.h>
#include <math.h>

// ---------------------------------------------------------------------------
// GCN 2-layer forward on MI355X.  ZERO global atomics.  7 launches.
//  FUSED [hist_lds (128 blocks x 100KB LDS packed 16-bit histograms, rank via
//         LDS-atomic return) || convw (W->bf16^T pair-permuted)]
//  -> scan2 (sum 128 replicas/node -> basecum ushort, dinv, exscan, blocksum)
//  -> blocksums_finalize (each block scans 196 sums in LDS, writes offsets)
//  -> FUSED [fill_csr (ushort csr, pos=offsets+basecum+rank, no atomics)
//            || mfma_gemm1 (x @ W1t, *dinv folded, bf16 h1)]
//  -> agg1 (bf16 gather, +b1, relu) -> mfma_gemm2 (*dinv) -> agg2 (log_softmax)
// R6-R8: global atomics pinned ~1.6e10/s (HW wall) -> LDS atomics only.
// R10: ~5.8us/launch gap -> fused convw+hist, merged scan tail; 64->128 hist
// blocks (2x CUs on the LDS-atomic phase); csr ushort halves scatter RMW.
// ---------------------------------------------------------------------------

typedef unsigned int uint32;
typedef unsigned short ushort16;
typedef __attribute__((ext_vector_type(8))) short bf16x8;
typedef __attribute__((ext_vector_type(4))) float f32x4;

__device__ inline unsigned short f2bf_rne(float f) {
    uint32 x = __float_as_uint(f);
    uint32 r = (x + 0x7fffu + ((x >> 16) & 1u)) >> 16;
    return (unsigned short)r;
}
__device__ inline uint32 pack_bf16x2(float a, float b) {
    return (uint32)f2bf_rne(a) | ((uint32)f2bf_rne(b) << 16);
}
__device__ inline float2 unpack_bf16x2(uint32 u) {
    float2 r;
    r.x = __uint_as_float(u << 16);
    r.y = __uint_as_float(u & 0xffff0000u);
    return r;
}

#define NHB 128  // histogram blocks / replicas

// FUSED: blocks [0,NHB): per-block LDS histogram (packed 2x16-bit counts),
//   rank = LDS-atomic old count; dump to counts_pb[b][NW].
// blocks [NHB,NHB+96): convw — W -> bf16 transposed, pair-permuted (slot
//   (t,m) holds logical col 32*(t>>1)+2*m+(t&1) so acc pairs pack adjacent).
__global__ __launch_bounds__(256) void hist_conv_k(const int* __restrict__ dst, int E,
                                                   int NW, int chunk,
                                                   uint32* __restrict__ counts_pb,
                                                   ushort16* __restrict__ rankx,
                                                   const float* __restrict__ W1,
                                                   const float* __restrict__ W2,
                                                   unsigned short* __restrict__ W1t,
                                                   unsigned short* __restrict__ W2t) {
    const int tid = threadIdx.x;
    if ((int)blockIdx.x >= NHB) {
        int idx = ((int)blockIdx.x - NHB) * 256 + tid;
        if (idx < 128 * 128) {
            int ns = idx >> 7, k = idx & 127;
            int t = ns >> 4, m = ns & 15;
            int col = 32 * (t >> 1) + 2 * m + (t & 1);
            W1t[idx] = f2bf_rne(W1[k * 128 + col]);
        } else {
            int i2 = idx - 128 * 128;
            if (i2 < 64 * 128) {
                int ns = i2 >> 7, k = i2 & 127;
                int t = ns >> 4, m = ns & 15;
                int col = 32 * (t >> 1) + 2 * m + (t & 1);
                W2t[i2] = f2bf_rne(W2[k * 64 + col]);
            }
        }
        return;
    }
    extern __shared__ uint32 sh[];
    const int b = blockIdx.x;
    for (int i = tid; i < NW; i += 256) sh[i] = 0;
    __syncthreads();
    const int e0 = b * chunk;
    const int e1 = min(E, e0 + chunk);
    int e = e0 + tid;
    for (; e + 768 < e1; e += 1024) {
        int d0 = dst[e];
        int d1 = dst[e + 256];
        int d2 = dst[e + 512];
        int d3 = dst[e + 768];
        uint32 o0 = atomicAdd(&sh[d0 >> 1], (d0 & 1) ? 0x10000u : 1u);
        uint32 o1 = atomicAdd(&sh[d1 >> 1], (d1 & 1) ? 0x10000u : 1u);
        uint32 o2 = atomicAdd(&sh[d2 >> 1], (d2 & 1) ? 0x10000u : 1u);
        uint32 o3 = atomicAdd(&sh[d3 >> 1], (d3 & 1) ? 0x10000u : 1u);
        rankx[e]       = (ushort16)((d0 & 1) ? (o0 >> 16) : (o0 & 0xffffu));
        rankx[e + 256] = (ushort16)((d1 & 1) ? (o1 >> 16) : (o1 & 0xffffu));
        rankx[e + 512] = (ushort16)((d2 & 1) ? (o2 >> 16) : (o2 & 0xffffu));
        rankx[e + 768] = (ushort16)((d3 & 1) ? (o3 >> 16) : (o3 & 0xffffu));
    }
    for (; e < e1; e += 256) {
        int d = dst[e];
        uint32 o = atomicAdd(&sh[d >> 1], (d & 1) ? 0x10000u : 1u);
        rankx[e] = (ushort16)((d & 1) ? (o >> 16) : (o & 0xffffu));
    }
    __syncthreads();
    uint32* dstp = counts_pb + (size_t)b * NW;
    for (int i = tid; i < NW; i += 256) dstp[i] = sh[i];
}

// Sum per-node counts over NHB block-histograms (16-way batched loads),
// emit basecum[b][n] (ushort), dinv, block-local exscan + blocksum.
__global__ __launch_bounds__(256) void scan2_k(const uint32* __restrict__ counts_pb,
                                               int N, int NW,
                                               ushort16* __restrict__ basecum,
                                               int* __restrict__ exscan,
                                               int* __restrict__ blocksum,
                                               float* __restrict__ dinv) {
    __shared__ int sd[256];
    const int tid = threadIdx.x;
    const int n   = blockIdx.x * 256 + tid;
    const int nc  = n < N ? n : N - 1;
    const int w   = nc >> 1;
    const bool hi = (nc & 1) != 0;
    int cum = 0;
    for (int bb = 0; bb < NHB; bb += 16) {
        uint32 wv[16];
#pragma unroll
        for (int j = 0; j < 16; ++j)
            wv[j] = counts_pb[(size_t)(bb + j) * NW + w];
#pragma unroll
        for (int j = 0; j < 16; ++j) {
            int c = hi ? (int)(wv[j] >> 16) : (int)(wv[j] & 0xffffu);
            if (n < N) basecum[(size_t)(bb + j) * N + n] = (ushort16)cum;
            cum += c;
        }
    }
    int v = (n < N) ? cum : 0;
    if (n < N) dinv[n] = rsqrtf((float)(v + 1));
    sd[tid] = v;
    __syncthreads();
    for (int off = 1; off < 256; off <<= 1) {
        int t = (tid >= off) ? sd[tid - off] : 0;
        __syncthreads();
        sd[tid] += t;
        __syncthreads();
    }
    if (n < N) exscan[n] = sd[tid] - v;
    if (tid == 255) blocksum[blockIdx.x] = sd[255];
}

// Every block redundantly scans the (<=256) blocksums in LDS, then writes
// offsets for its 256-node slice.  Replaces scan_blocksums + finalize.
__global__ __launch_bounds__(256) void blocksums_finalize_k(const int* __restrict__ blocksum,
                                                            int NB,
                                                            const int* __restrict__ exscan,
                                                            int N,
                                                            int* __restrict__ offsets) {
    __shared__ int sd[256];
    __shared__ int boff;
    const int tid = threadIdx.x;
    int v = (tid < NB) ? blocksum[tid] : 0;
    sd[tid] = v;
    __syncthreads();
    for (int off = 1; off < 256; off <<= 1) {
        int t = (tid >= off) ? sd[tid - off] : 0;
        __syncthreads();
        sd[tid] += t;
        __syncthreads();
    }
    if (tid == 0) boff = sd[blockIdx.x] - blocksum[blockIdx.x];
    __syncthreads();
    const int gid = blockIdx.x * 256 + tid;
    if (gid < N) offsets[gid] = boff + exscan[gid];
    if (blockIdx.x == 0 && tid == 0) offsets[N] = sd[255];
}

// FUSED: blocks [0,256): fill CSR (ushort src); fill block f covers half
//   (f&1) of hist chunk b=f>>1:  pos = offsets[d] + basecum[b][d] + rank.
// blocks [256,256+GB): mfma gemm1 h1 = bf16((x @ W1t) * dinv).
__global__ __launch_bounds__(256) void fill_gemm1_k(const int* __restrict__ src,
                                                    const int* __restrict__ dst, int E,
                                                    int chunk, int N,
                                                    const ushort16* __restrict__ rankx,
                                                    const ushort16* __restrict__ basecum,
                                                    const int* __restrict__ offsets,
                                                    ushort16* __restrict__ csr_src,
                                                    const float* __restrict__ X,
                                                    const unsigned short* __restrict__ Wt,
                                                    const float* __restrict__ dinv,
                                                    uint32* __restrict__ Yu, int Nrows) {
    if ((int)blockIdx.x < 256) {
        const int f  = blockIdx.x;
        const int b  = f >> 1;
        const ushort16* bc = basecum + (size_t)b * N;
        const int q2 = chunk >> 1;
        const int e0 = b * chunk + (f & 1) * q2;
        const int e1 = min(E, e0 + q2);
        int e = e0 + threadIdx.x;
        for (; e + 768 < e1; e += 1024) {
#pragma unroll
            for (int j = 0; j < 4; ++j) {
                int ej = e + j * 256;
                int d = dst[ej];
                int pos = offsets[d] + (int)bc[d] + (int)rankx[ej];
                csr_src[pos] = (ushort16)src[ej];
            }
        }
        for (; e < e1; e += 256) {
            int d = dst[e];
            int pos = offsets[d] + (int)bc[d] + (int)rankx[e];
            csr_src[pos] = (ushort16)src[e];
        }
        return;
    }
    // ---- gemm1 part (NCOL=128, fp32 A converted in-register, *dinv) ----
    constexpr int NCOL = 128;
    constexpr int NT = NCOL / 16;
    const int tid  = threadIdx.x;
    const int wave = tid >> 6;
    const int lane = tid & 63;
    const int m16  = lane & 15;
    const int q    = lane >> 4;
    const int r0   = ((int)blockIdx.x - 256) * 64 + wave * 16;

    int arow = r0 + m16;
    if (arow >= Nrows) arow = Nrows - 1;

    bf16x8 afrag[4];
#pragma unroll
    for (int kb = 0; kb < 4; ++kb) {
        const float* p = &X[(size_t)arow * 128 + kb * 32 + q * 8];
        float4 u0 = *(const float4*)p;
        float4 u1 = *(const float4*)(p + 4);
        bf16x8 a;
        a[0] = (short)f2bf_rne(u0.x); a[1] = (short)f2bf_rne(u0.y);
        a[2] = (short)f2bf_rne(u0.z); a[3] = (short)f2bf_rne(u0.w);
        a[4] = (short)f2bf_rne(u1.x); a[5] = (short)f2bf_rne(u1.y);
        a[6] = (short)f2bf_rne(u1.z); a[7] = (short)f2bf_rne(u1.w);
        afrag[kb] = a;
    }

    f32x4 acc[NT];
#pragma unroll
    for (int t = 0; t < NT; ++t) acc[t] = (f32x4){0.f, 0.f, 0.f, 0.f};
#pragma unroll
    for (int t = 0; t < NT; ++t) {
        const unsigned short* Bp = &Wt[(size_t)(t * 16 + m16) * 128 + q * 8];
#pragma unroll
        for (int kb = 0; kb < 4; ++kb) {
            bf16x8 bfrag = *(const bf16x8*)&Bp[kb * 32];
            acc[t] = __builtin_amdgcn_mfma_f32_16x16x32_bf16(afrag[kb], bfrag, acc[t], 0, 0, 0);
        }
    }
#pragma unroll
    for (int i = 0; i < 4; ++i) {
        int row = r0 + q * 4 + i;
        if (row < Nrows) {
            float dn = dinv[row];
#pragma unroll
            for (int u = 0; u < NT / 2; ++u)
                Yu[(size_t)row * (NCOL / 2) + u * 16 + m16] =
                    pack_bf16x2(acc[2 * u][i] * dn, acc[2 * u + 1][i] * dn);
        }
    }
}

// MFMA GEMM2: h2[r,:] = bf16( (h1a[r,:128] @ W2t) * dinv[r] ), pair-packed.
__global__ __launch_bounds__(256) void mfma_gemm2_k(const unsigned short* __restrict__ X,
                                                    const unsigned short* __restrict__ Wt,
                                                    const float* __restrict__ dinv,
                                                    uint32* __restrict__ Yu, int Nrows) {
    constexpr int NCOL = 64;
    constexpr int NT = NCOL / 16;
    const int tid  = threadIdx.x;
    const int wave = tid >> 6;
    const int lane = tid & 63;
    const int m16  = lane & 15;
    const int q    = lane >> 4;
    const int r0   = blockIdx.x * 64 + wave * 16;

    int arow = r0 + m16;
    if (arow >= Nrows) arow = Nrows - 1;

    bf16x8 afrag[4];
#pragma unroll
    for (int kb = 0; kb < 4; ++kb)
        afrag[kb] = *(const bf16x8*)&X[(size_t)arow * 128 + kb * 32 + q * 8];

    f32x4 acc[NT];
#pragma unroll
    for (int t = 0; t < NT; ++t) acc[t] = (f32x4){0.f, 0.f, 0.f, 0.f};
#pragma unroll
    for (int t = 0; t < NT; ++t) {
        const unsigned short* Bp = &Wt[(size_t)(t * 16 + m16) * 128 + q * 8];
#pragma unroll
        for (int kb = 0; kb < 4; ++kb) {
            bf16x8 bfrag = *(const bf16x8*)&Bp[kb * 32];
            acc[t] = __builtin_amdgcn_mfma_f32_16x16x32_bf16(afrag[kb], bfrag, acc[t], 0, 0, 0);
        }
    }
#pragma unroll
    for (int i = 0; i < 4; ++i) {
        int row = r0 + q * 4 + i;
        if (row < Nrows) {
            float dn = dinv[row];
#pragma unroll
            for (int u = 0; u < NT / 2; ++u)
                Yu[(size_t)row * (NCOL / 2) + u * 16 + m16] =
                    pack_bf16x2(acc[2 * u][i] * dn, acc[2 * u + 1][i] * dn);
        }
    }
}

// Layer-1 aggregation: 64 lanes/node, 2 ch/lane, 4 nodes/block, x4 unroll.
__global__ __launch_bounds__(256) void agg1_k(const unsigned short* __restrict__ hs,
                                              const int* __restrict__ offsets,
                                              const ushort16* __restrict__ csr_src,
                                              const float* __restrict__ dinv,
                                              const float* __restrict__ b1,
                                              unsigned short* __restrict__ out, int N) {
    const int tid  = threadIdx.x;
    const int node = blockIdx.x * 4 + (tid >> 6);
    const int lane = tid & 63;
    if (node >= N) return;
    const uint32* T = (const uint32*)hs;
    const int start = offsets[node];
    const int end   = offsets[node + 1];
    const float dn  = dinv[node];
    float2 self = unpack_bf16x2(T[(size_t)node * 64 + lane]);
    float ax0 = self.x, ay0 = self.y;
    float ax1 = 0.f, ay1 = 0.f, ax2 = 0.f, ay2 = 0.f, ax3 = 0.f, ay3 = 0.f;
    int p = start;
    for (; p + 3 < end; p += 4) {
        int s0 = csr_src[p];
        int s1 = csr_src[p + 1];
        int s2 = csr_src[p + 2];
        int s3 = csr_src[p + 3];
        float2 f0 = unpack_bf16x2(T[(size_t)s0 * 64 + lane]);
        float2 f1 = unpack_bf16x2(T[(size_t)s1 * 64 + lane]);
        float2 f2 = unpack_bf16x2(T[(size_t)s2 * 64 + lane]);
        float2 f3 = unpack_bf16x2(T[(size_t)s3 * 64 + lane]);
        ax0 += f0.x; ay0 += f0.y;
        ax1 += f1.x; ay1 += f1.y;
        ax2 += f2.x; ay2 += f2.y;
        ax3 += f3.x; ay3 += f3.y;
    }
    for (; p < end; ++p) {
        float2 f = unpack_bf16x2(T[(size_t)csr_src[p] * 64 + lane]);
        ax1 += f.x; ay1 += f.y;
    }
    float2 bb = ((const float2*)b1)[lane];
    float vx = ((ax0 + ax1) + (ax2 + ax3)) * dn + bb.x;
    float vy = ((ay0 + ay1) + (ay2 + ay3)) * dn + bb.y;
    vx = vx > 0.f ? vx : 0.f;
    vy = vy > 0.f ? vy : 0.f;
    ((uint32*)out)[(size_t)node * 64 + lane] = pack_bf16x2(vx, vy);
}

// Layer-2 aggregation + bias + log_softmax. 32 lanes/node, 8 nodes/block.
__global__ __launch_bounds__(256) void agg2_k(const unsigned short* __restrict__ hs,
                                              const int* __restrict__ offsets,
                                              const ushort16* __restrict__ csr_src,
                                              const float* __restrict__ dinv,
                                              const float* __restrict__ b2,
                                              float* __restrict__ out, int N) {
    const int tid  = threadIdx.x;
    const int node = blockIdx.x * 8 + (tid >> 5);
    const int l    = tid & 31;
    if (node >= N) return;
    const uint32* T = (const uint32*)hs;
    const int start = offsets[node];
    const int end   = offsets[node + 1];
    const float dn  = dinv[node];
    float2 self = unpack_bf16x2(T[(size_t)node * 32 + l]);
    float ax0 = self.x, ay0 = self.y;
    float ax1 = 0.f, ay1 = 0.f, ax2 = 0.f, ay2 = 0.f, ax3 = 0.f, ay3 = 0.f;
    int p = start;
    for (; p + 3 < end; p += 4) {
        int s0 = csr_src[p];
        int s1 = csr_src[p + 1];
        int s2 = csr_src[p + 2];
        int s3 = csr_src[p + 3];
        float2 f0 = unpack_bf16x2(T[(size_t)s0 * 32 + l]);
        float2 f1 = unpack_bf16x2(T[(size_t)s1 * 32 + l]);
        float2 f2 = unpack_bf16x2(T[(size_t)s2 * 32 + l]);
        float2 f3 = unpack_bf16x2(T[(size_t)s3 * 32 + l]);
        ax0 += f0.x; ay0 += f0.y;
        ax1 += f1.x; ay1 += f1.y;
        ax2 += f2.x; ay2 += f2.y;
        ax3 += f3.x; ay3 += f3.y;
    }
    for (; p < end; ++p) {
        float2 f = unpack_bf16x2(T[(size_t)csr_src[p] * 32 + l]);
        ax1 += f.x; ay1 += f.y;
    }
    float2 bb = ((const float2*)b2)[l];
    float vx = ((ax0 + ax1) + (ax2 + ax3)) * dn + bb.x;
    float vy = ((ay0 + ay1) + (ay2 + ay3)) * dn + bb.y;
    float m = fmaxf(vx, vy);
#pragma unroll
    for (int off = 16; off > 0; off >>= 1) m = fmaxf(m, __shfl_xor(m, off, 64));
    float ex = __expf(vx - m) + __expf(vy - m);
    float ssum = ex;
#pragma unroll
    for (int off = 16; off > 0; off >>= 1) ssum += __shfl_xor(ssum, off, 64);
    float lse = m + __logf(ssum);
    float2 o = {vx - lse, vy - lse};
    ((float2*)out)[(size_t)node * 32 + l] = o;
}

extern "C" void kernel_launch(void* const* d_in, const int* in_sizes, int n_in,
                              void* d_out, int out_size, void* d_ws, size_t ws_size,
                              hipStream_t stream) {
    const float* x  = (const float*)d_in[0];
    const int*   ei = (const int*)d_in[1];
    const float* W1 = (const float*)d_in[2];
    const float* b1 = (const float*)d_in[3];
    const float* W2 = (const float*)d_in[4];
    const float* b2 = (const float*)d_in[5];
    float* out = (float*)d_out;

    const int N = in_sizes[0] / 128;  // 50000
    const int E = in_sizes[1] / 2;    // 800000
    const int* src = ei;
    const int* dst = ei + E;
    const int NB = (N + 255) / 256;        // 196
    const int NW = (N + 1) / 2;            // 25000 packed count words
    const int chunk = (E + NHB - 1) / NHB; // 6250 edges per hist block

    char* ws = (char*)d_ws;
    auto alloc = [&](size_t bytes) -> char* {
        char* p = ws;
        ws += (bytes + 255) & ~(size_t)255;
        return p;
    };
    unsigned short* h1  = (unsigned short*)alloc((size_t)N * 128 * 2);   // 12.8MB
    unsigned short* h1a = (unsigned short*)alloc((size_t)N * 128 * 2);   // 12.8MB
    unsigned short* h2  = (unsigned short*)alloc((size_t)N * 64 * 2);    // 6.4MB
    uint32* counts_pb = (uint32*)alloc((size_t)NHB * NW * 4);            // 12.8MB
    ushort16* basecum = (ushort16*)alloc((size_t)NHB * N * 2);           // 12.8MB
    ushort16* rankx   = (ushort16*)alloc((size_t)E * 2);                 // 1.6MB
    ushort16* csr_src = (ushort16*)alloc((size_t)E * 2);                 // 1.6MB
    float* dinv     = (float*)alloc((size_t)N * 4);
    int*   exscan   = (int*)alloc((size_t)N * 4);
    int*   blocksum = (int*)alloc((size_t)NB * 4);
    int*   offsets  = (int*)alloc((size_t)(N + 1) * 4);
    unsigned short* W1t = (unsigned short*)alloc(128 * 128 * 2);
    unsigned short* W2t = (unsigned short*)alloc(64 * 128 * 2);

    const int GB = (N + 63) / 64;          // 782 gemm blocks
    const int CB = (128 * 128 + 64 * 128 + 255) / 256;  // 96 convw blocks

    hist_conv_k<<<NHB + CB, 256, NW * 4, stream>>>(dst, E, NW, chunk, counts_pb, rankx,
                                                   W1, W2, W1t, W2t);
    scan2_k<<<NB, 256, 0, stream>>>(counts_pb, N, NW, basecum, exscan, blocksum, dinv);
    blocksums_finalize_k<<<NB, 256, 0, stream>>>(blocksum, NB, exscan, N, offsets);
    fill_gemm1_k<<<256 + GB, 256, 0, stream>>>(src, dst, E, chunk, N, rankx, basecum,
                                               offsets, csr_src, x, W1t, dinv,
                                               (uint32*)h1, N);
    agg1_k<<<(N + 3) / 4, 256, 0, stream>>>(h1, offsets, csr_src, dinv, b1, h1a, N);
    mfma_gemm2_k<<<GB, 256, 0, stream>>>(h1a, W2t, dinv, (uint32*)h2, N);
    agg2_k<<<(N + 7) / 8, 256, 0, stream>>>(h2, offsets, csr_src, dinv, b2, out, N);
}